// Round 1
// baseline (75.195 us; speedup 1.0000x reference)
//
#include <hip/hip_runtime.h>

// Problem constants (fixed by the reference):
constexpr int BATCH = 256;
constexpr int CH    = 512;
constexpr int KS    = 5;
constexpr int PAD   = (KS - 1) / 2;  // 'same' padding = 2
constexpr float LOG2E = 1.4426950408889634f;

// d_ws layout (floats):
//   [0,           B*CH)   : qh2  = conv(q) * log2e
//   [B*CH,      2*B*CH)   : kh   = conv(k)
//   [2*B*CH,    3*B*CH)   : vh   = conv(v)
//   [3*B*CH, 3*B*CH+2*B)  : kstat = {kmax, kmin} per batch
// Total ~1.5 MB, well under the 256 MB workspace. Every word we read is
// rewritten by conv_stats_kernel each iteration, so re-poisoning is safe.

// ---------------------------------------------------------------------------
// Kernel A: conv1d (cross-correlation, 'same', zero-pad) + per-batch k-stats.
// One block per batch, one thread per channel. Memory-trivial (~3 MB total).
// ---------------------------------------------------------------------------
__global__ __launch_bounds__(CH, 2) void conv_stats_kernel(
    const float* __restrict__ q, const float* __restrict__ k, const float* __restrict__ v,
    const float* __restrict__ wq, const float* __restrict__ wk, const float* __restrict__ wv,
    float* __restrict__ ws)
{
    __shared__ float sq[CH], sk[CH], sv[CH];
    __shared__ float wred_max[8], wred_min[8];

    const int b = blockIdx.x;
    const int t = threadIdx.x;

    sq[t] = q[b * CH + t];
    sk[t] = k[b * CH + t];
    sv[t] = v[b * CH + t];

    float w_q[KS], w_k[KS], w_v[KS];
#pragma unroll
    for (int j = 0; j < KS; ++j) { w_q[j] = wq[j]; w_k[j] = wk[j]; w_v[j] = wv[j]; }
    __syncthreads();

    float aq = 0.f, ak = 0.f, av = 0.f;
#pragma unroll
    for (int j = 0; j < KS; ++j) {
        const int idx = t + j - PAD;
        if (idx >= 0 && idx < CH) {
            aq = fmaf(sq[idx], w_q[j], aq);
            ak = fmaf(sk[idx], w_k[j], ak);
            av = fmaf(sv[idx], w_v[j], av);
        }
    }

    // qh pre-scaled by log2e so the hot loop can use raw v_exp_f32 (exp2).
    ws[b * CH + t]                 = aq * LOG2E;
    ws[(BATCH + b) * CH + t]       = ak;
    ws[(2 * BATCH + b) * CH + t]   = av;

    // Block max/min of kh -> exact per-row score max for stable softmax.
    float lmax = ak, lmin = ak;
#pragma unroll
    for (int off = 32; off > 0; off >>= 1) {
        lmax = fmaxf(lmax, __shfl_down(lmax, off, 64));
        lmin = fminf(lmin, __shfl_down(lmin, off, 64));
    }
    const int wave = t >> 6;
    if ((t & 63) == 0) { wred_max[wave] = lmax; wred_min[wave] = lmin; }
    __syncthreads();
    if (t == 0) {
        float m = wred_max[0], n = wred_min[0];
#pragma unroll
        for (int i = 1; i < 8; ++i) { m = fmaxf(m, wred_max[i]); n = fminf(n, wred_min[i]); }
        float* kstat = ws + 3 * BATCH * CH;
        kstat[2 * b]     = m;
        kstat[2 * b + 1] = n;
    }
}

// ---------------------------------------------------------------------------
// Kernel B: rank-1 attention. 1024 threads/block: c = t&511 owns an output
// row, h = t>>9 owns half the d-range (doubles occupancy to 4 waves/SIMD).
// kh/vh addresses are wave-uniform (readfirstlane'd h, uniform loop index,
// no aliasing stores) -> backend emits s_load into SGPRs; the hot loop is
// 3 VALU + 1 v_exp_f32 per d with zero LDS / zero vector-memory traffic.
// ---------------------------------------------------------------------------
__global__ __launch_bounds__(1024, 4) void attn1d_kernel(
    const float* __restrict__ qh2g, const float* __restrict__ khg,
    const float* __restrict__ vhg,  const float* __restrict__ kstat,
    float* __restrict__ out)
{
    __shared__ float redd[CH], redn[CH];

    const int b = blockIdx.x;
    const int t = threadIdx.x;
    const int c = t & (CH - 1);
    // t>>9 is constant across each 64-lane wave; force the compiler to see it
    // as wave-uniform so kh/vh loads scalarize.
    const int h = __builtin_amdgcn_readfirstlane(t >> 9);

    const float qc2 = qh2g[b * CH + c];          // qh[c] * log2e (coalesced)
    const float kmax = kstat[2 * b];
    const float kmin = kstat[2 * b + 1];
    // Exact row max of qc*kh[d] in log2 domain (sign-selected extreme).
    const float m2  = (qc2 >= 0.f) ? qc2 * kmax : qc2 * kmin;
    const float nm2 = -m2;

    const float4* __restrict__ k4 = (const float4*)(khg + b * CH + h * (CH / 2));
    const float4* __restrict__ v4 = (const float4*)(vhg + b * CH + h * (CH / 2));

    // 4 independent accumulator chains per side: dep distance = 1 iter.
    float den0 = 0.f, den1 = 0.f, den2 = 0.f, den3 = 0.f;
    float num0 = 0.f, num1 = 0.f, num2 = 0.f, num3 = 0.f;
#pragma unroll 4
    for (int i = 0; i < (CH / 2) / 4; ++i) {     // 64 iters x 4 d
        const float4 kk = k4[i];                 // wave-uniform -> s_load
        const float4 vv = v4[i];
        const float e0 = __builtin_amdgcn_exp2f(fmaf(qc2, kk.x, nm2));
        const float e1 = __builtin_amdgcn_exp2f(fmaf(qc2, kk.y, nm2));
        const float e2 = __builtin_amdgcn_exp2f(fmaf(qc2, kk.z, nm2));
        const float e3 = __builtin_amdgcn_exp2f(fmaf(qc2, kk.w, nm2));
        den0 += e0; den1 += e1; den2 += e2; den3 += e3;
        num0 = fmaf(e0, vv.x, num0);
        num1 = fmaf(e1, vv.y, num1);
        num2 = fmaf(e2, vv.z, num2);
        num3 = fmaf(e3, vv.w, num3);
    }
    const float den = (den0 + den1) + (den2 + den3);
    const float num = (num0 + num1) + (num2 + num3);

    // Combine the two d-halves (same m2 on both sides by construction).
    if (h == 1) { redd[c] = den; redn[c] = num; }
    __syncthreads();
    if (h == 0) out[b * CH + c] = (num + redn[c]) / (den + redd[c]);
}

extern "C" void kernel_launch(void* const* d_in, const int* in_sizes, int n_in,
                              void* d_out, int out_size, void* d_ws, size_t ws_size,
                              hipStream_t stream) {
    const float* q  = (const float*)d_in[0];
    const float* k  = (const float*)d_in[1];
    const float* v  = (const float*)d_in[2];
    const float* wq = (const float*)d_in[3];
    const float* wk = (const float*)d_in[4];
    const float* wv = (const float*)d_in[5];
    float* out = (float*)d_out;
    float* ws  = (float*)d_ws;

    conv_stats_kernel<<<BATCH, CH, 0, stream>>>(q, k, v, wq, wk, wv, ws);

    const float* qh2g  = ws;
    const float* khg   = ws + BATCH * CH;
    const float* vhg   = ws + 2 * BATCH * CH;
    const float* kstat = ws + 3 * BATCH * CH;
    attn1d_kernel<<<BATCH, 1024, 0, stream>>>(qh2g, khg, vhg, kstat, out);
}

// Round 2
// 72.977 us; speedup vs baseline: 1.0304x; 1.0304x over previous
//
#include <hip/hip_runtime.h>

// Problem constants (fixed by the reference):
constexpr int BATCH = 256;
constexpr int CH    = 512;
constexpr int KS    = 5;
constexpr int PAD   = (KS - 1) / 2;  // 'same' padding = 2
constexpr float LOG2E = 1.4426950408889634f;

// Fully fused: conv + stats + rank-1 softmax attention in ONE launch.
// One block per batch, 1024 threads = 16 waves/CU (4/SIMD).
//
// Hot-loop economics (per CU = per batch):
//   - 4 c-rows per thread: one kh4/vh4 LDS broadcast pair feeds 16 exps
//     -> 512 ds_read_b128 per batch (~6k cyc, ~2.6 us) vs 2048 in the
//     1-row/thread version (~10.2 us). LDS pipe no longer the floor.
//   - VALU/trans floor: 3 VALU + 1 v_exp_f32 per (c,d); log2e folded into
//     qh so exp is a raw exp2. ~4.3 us/SIMD lower bound.
// d-range is split 8 ways (g = t>>7) for occupancy; partial num/den are
// combined through a 32 KB LDS buffer (cheap: ~256 instrs).
__global__ __launch_bounds__(1024, 1) void fused_attn1d_kernel(
    const float* __restrict__ q, const float* __restrict__ k, const float* __restrict__ v,
    const float* __restrict__ wq, const float* __restrict__ wk, const float* __restrict__ wv,
    float* __restrict__ out)
{
    __shared__ __align__(16) float sq[CH], sk[CH], sv[CH];
    __shared__ __align__(16) float qh2[CH], kh[CH], vh[CH];
    __shared__ float2 red[8][CH];          // per-d-group partial {num, den}, 32 KB
    __shared__ float wred_max[8], wred_min[8];
    __shared__ float s_kmax, s_kmin;

    const int b = blockIdx.x;
    const int t = threadIdx.x;

    // ---- stage raw rows (threads 0..511, coalesced dword) ----
    if (t < CH) {
        sq[t] = q[b * CH + t];
        sk[t] = k[b * CH + t];
        sv[t] = v[b * CH + t];
    }
    __syncthreads();

    // ---- conv ('same' cross-correlation, zero-pad) + k-stats ----
    if (t < CH) {
        float w_q[KS], w_k[KS], w_v[KS];
#pragma unroll
        for (int j = 0; j < KS; ++j) { w_q[j] = wq[j]; w_k[j] = wk[j]; w_v[j] = wv[j]; }

        float aq = 0.f, ak = 0.f, av = 0.f;
#pragma unroll
        for (int j = 0; j < KS; ++j) {
            const int idx = t + j - PAD;
            if (idx >= 0 && idx < CH) {
                aq = fmaf(sq[idx], w_q[j], aq);
                ak = fmaf(sk[idx], w_k[j], ak);
                av = fmaf(sv[idx], w_v[j], av);
            }
        }
        qh2[t] = aq * LOG2E;   // pre-scale so hot loop uses raw exp2
        kh[t]  = ak;
        vh[t]  = av;

        // wave-level max/min of kh (8 waves participate)
        float lmax = ak, lmin = ak;
#pragma unroll
        for (int off = 32; off > 0; off >>= 1) {
            lmax = fmaxf(lmax, __shfl_down(lmax, off, 64));
            lmin = fminf(lmin, __shfl_down(lmin, off, 64));
        }
        if ((t & 63) == 0) { wred_max[t >> 6] = lmax; wred_min[t >> 6] = lmin; }
    }
    __syncthreads();
    if (t == 0) {
        float m = wred_max[0], n = wred_min[0];
#pragma unroll
        for (int i = 1; i < 8; ++i) { m = fmaxf(m, wred_max[i]); n = fminf(n, wred_min[i]); }
        s_kmax = m; s_kmin = n;
    }
    __syncthreads();

    // ---- rank-1 attention: g = d-group (8 x 64 d), li covers 4 c-rows ----
    const int g  = t >> 7;          // 0..7
    const int li = t & 127;         // c rows: li, li+128, li+256, li+384

    float qr[4], nm2[4];
    float den[4] = {0.f, 0.f, 0.f, 0.f};
    float num[4] = {0.f, 0.f, 0.f, 0.f};
#pragma unroll
    for (int r = 0; r < 4; ++r) {
        const float qc2 = qh2[li + 128 * r];
        qr[r]  = qc2;
        // exact row max of qc*kh[d] in log2 domain (sign-selected extreme)
        nm2[r] = -((qc2 >= 0.f) ? qc2 * s_kmax : qc2 * s_kmin);
    }

    const float4* kh4 = (const float4*)kh;
    const float4* vh4 = (const float4*)vh;
    const int base = g * 16;        // 16 float4 chunks = 64 d per group
#pragma unroll 4
    for (int i = 0; i < 16; ++i) {
        const float4 kk = kh4[base + i];   // wave-uniform LDS broadcast
        const float4 vv = vh4[base + i];
#pragma unroll
        for (int r = 0; r < 4; ++r) {
            const float e0 = __builtin_amdgcn_exp2f(fmaf(qr[r], kk.x, nm2[r]));
            const float e1 = __builtin_amdgcn_exp2f(fmaf(qr[r], kk.y, nm2[r]));
            const float e2 = __builtin_amdgcn_exp2f(fmaf(qr[r], kk.z, nm2[r]));
            const float e3 = __builtin_amdgcn_exp2f(fmaf(qr[r], kk.w, nm2[r]));
            den[r] += (e0 + e1) + (e2 + e3);
            num[r] = fmaf(e0, vv.x, num[r]);
            num[r] = fmaf(e1, vv.y, num[r]);
            num[r] = fmaf(e2, vv.z, num[r]);
            num[r] = fmaf(e3, vv.w, num[r]);
        }
    }
#pragma unroll
    for (int r = 0; r < 4; ++r) red[g][li + 128 * r] = make_float2(num[r], den[r]);
    __syncthreads();

    // ---- combine the 8 d-group partials, write out ----
    if (t < CH) {
        float n = 0.f, d = 0.f;
#pragma unroll
        for (int g2 = 0; g2 < 8; ++g2) {
            const float2 p = red[g2][t];
            n += p.x; d += p.y;
        }
        out[b * CH + t] = n / d;
    }
}

extern "C" void kernel_launch(void* const* d_in, const int* in_sizes, int n_in,
                              void* d_out, int out_size, void* d_ws, size_t ws_size,
                              hipStream_t stream) {
    const float* q  = (const float*)d_in[0];
    const float* k  = (const float*)d_in[1];
    const float* v  = (const float*)d_in[2];
    const float* wq = (const float*)d_in[3];
    const float* wk = (const float*)d_in[4];
    const float* wv = (const float*)d_in[5];
    float* out = (float*)d_out;
    (void)d_ws; (void)ws_size;

    fused_attn1d_kernel<<<BATCH, 1024, 0, stream>>>(q, k, v, wq, wk, wv, out);
}